// Round 1
// baseline (1112.254 us; speedup 1.0000x reference)
//
#include <hip/hip_runtime.h>
#include <hip/hip_bf16.h>

// Problem constants (fixed by reference setup_inputs)
constexpr int T_DIM = 10;
constexpr int C_DIM = 3;
constexpr int H_DIM = 512;
constexpr int W_DIM = 512;
constexpr int PT = 2;
constexpr int PS = 7;
constexpr int ELEM_PER_Q = PT * C_DIM * PS * PS;  // 294

__global__ __launch_bounds__(256) void ScatterNL_scatter_kernel(
    const float* __restrict__ patches,
    const int* __restrict__ qinds,
    float* __restrict__ out,
    int total)  // total = Q * 294
{
    int e = blockIdx.x * blockDim.x + threadIdx.x;
    if (e >= total) return;

    // Decompose e -> (q, dt, c, i, j). Constant divisors -> compiler magic-mul.
    int q  = e / ELEM_PER_Q;
    int r  = e - q * ELEM_PER_Q;
    int dt = r / (C_DIM * PS * PS);
    int r2 = r - dt * (C_DIM * PS * PS);
    int c  = r2 / (PS * PS);
    int r3 = r2 - c * (PS * PS);
    int i  = r3 / PS;
    int j  = r3 - i * PS;

    int t = qinds[3 * q + 0] + dt;
    int h = qinds[3 * q + 1] + i;
    int w = qinds[3 * q + 2] + j;

    float v = patches[e];  // coalesced: lane i reads element e0+i

    int idx = ((t * C_DIM + c) * H_DIM + h) * W_DIM + w;
    atomicAdd(&out[idx], v);
}

extern "C" void kernel_launch(void* const* d_in, const int* in_sizes, int n_in,
                              void* d_out, int out_size, void* d_ws, size_t ws_size,
                              hipStream_t stream) {
    const float* vid2fill = (const float*)d_in[0];
    const float* patches  = (const float*)d_in[1];
    const int*   qinds    = (const int*)d_in[2];
    float* out = (float*)d_out;

    int Q = in_sizes[2] / 3;
    int total = Q * ELEM_PER_Q;

    // out = vid2fill (all zeros in setup, but be faithful), then scatter-add.
    hipMemcpyAsync(out, vid2fill, (size_t)out_size * sizeof(float),
                   hipMemcpyDeviceToDevice, stream);

    int block = 256;
    int grid = (total + block - 1) / block;
    ScatterNL_scatter_kernel<<<grid, block, 0, stream>>>(patches, qinds, out, total);
}